// Round 9
// baseline (518.607 us; speedup 1.0000x reference)
//
#include <hip/hip_runtime.h>
#include <stdint.h>

#define VOCAB 28996
#define EMBED 512
#define NROWS 8192
#define VPAD  29056  /* 227 * 128 */
#define LOG2E 1.4426950408889634f
#define WSCALE 16.0f
#define INV_WSCALE_L2E (LOG2E / 16.0f)

typedef __attribute__((ext_vector_type(8)))  int   i32x8;
typedef __attribute__((ext_vector_type(16))) float f32x16;

// pack 4 floats -> 4 x fp8 e4m3 (OCP, RNE, saturating) in one i32
__device__ __forceinline__ int pk_fp8x4(float a, float b, float c, float d) {
  int r = __builtin_amdgcn_cvt_pk_fp8_f32(a, b, 0, false);
  r = __builtin_amdgcn_cvt_pk_fp8_f32(c, d, r, true);
  return r;
}

// ---- fused prep (IDENTICAL to the harness-verified round-0 kernel) ----
// blocks [0,7264): W   (VPAD*512/8/256 = 7264)
// blocks [7264,9312): x (8192*512/8/256 = 2048)
// blocks [9312,11360): py (1 wave/row, 4 rows/block)
// blocks [11360,11392): zero sg
__global__ void __launch_bounds__(256)
prep_kernel(const float* __restrict__ x, const float* __restrict__ W,
            const float* __restrict__ b, const int* __restrict__ y,
            int* __restrict__ xb, int* __restrict__ wb,
            float* __restrict__ py, float* __restrict__ sg) {
  const int bid = blockIdx.x;
  if (bid < 7264) {                        // ---- cvt W*16 -> fp8 ----
    int i = (bid * 256 + threadIdx.x) * 8; // float index; VK multiple of 8
    const int VK = VOCAB * EMBED;
    int2 o;
    if (i < VK) {
      float4 v0 = *(const float4*)(W + i);
      float4 v1 = *(const float4*)(W + i + 4);
      o.x = pk_fp8x4(v0.x * WSCALE, v0.y * WSCALE, v0.z * WSCALE, v0.w * WSCALE);
      o.y = pk_fp8x4(v1.x * WSCALE, v1.y * WSCALE, v1.z * WSCALE, v1.w * WSCALE);
    } else { o.x = 0; o.y = 0; }
    *(int2*)(wb + i / 4) = o;
  } else if (bid < 9312) {                 // ---- cvt x -> fp8 ----
    int i = ((bid - 7264) * 256 + threadIdx.x) * 8;
    float4 v0 = *(const float4*)(x + i);
    float4 v1 = *(const float4*)(x + i + 4);
    int2 o;
    o.x = pk_fp8x4(v0.x, v0.y, v0.z, v0.w);
    o.y = pk_fp8x4(v1.x, v1.y, v1.z, v1.w);
    *(int2*)(xb + i / 4) = o;
  } else if (bid < 11360) {                // ---- py: e^{x.W[y]+b[y]}, fp32 exact ----
    const int row  = ((bid - 9312) * 256 + threadIdx.x) >> 6;
    const int lane = threadIdx.x & 63;
    const int yr = y[row];
    const float4* xr = (const float4*)(x + (size_t)row * EMBED);
    const float4* wr = (const float4*)(W + (size_t)yr * EMBED);
    float d = 0.f;
#pragma unroll
    for (int t = 0; t < 2; ++t) {
      float4 a = xr[lane * 2 + t], c = wr[lane * 2 + t];
      d += a.x * c.x + a.y * c.y + a.z * c.z + a.w * c.w;
    }
#pragma unroll
    for (int m = 1; m < 64; m <<= 1) d += __shfl_xor(d, m);
    if (lane == 0) py[row] = __expf(d + b[yr]);
  } else {                                 // ---- zero sg ----
    int i = (bid - 11360) * 256 + threadIdx.x;
    sg[i] = 0.f;
  }
}

// ---- fused GEMM (16*logits = x . (16W)^T, MX-fp8 32x32x64) + row-sum exp ----
// Round-9 = round-8 resubmitted (container infra flake; kernel re-audited:
// no OOB, no barriers, regs ~150 < 170 cap).
// DIRECT-FROM-L2 register GEMM — NO LDS, NO BARRIERS.
// Rationale (r0..r7 cycle accounting): r0 is LDS-pipe-saturated (~113%
// demand), r7 is stall-bound at 50% LDS busy; no tile geometry fits the
// register file in between. But LDS earns nothing here: B has ZERO
// intra-block reuse (each wave reads a disjoint 64-col slice — staging is a
// pure pass-through), A is reused only 4x and the kt working set (48 KB)
// L1/L2-fits. So load MFMA fragments straight from global into registers:
//   lane (l31,h) of wave (wr,wc): operand bytes
//     A: xb[(rowBase+wr+ii*32+l31)*512 + kt*128 + kk*64 + h*32 ..+32)
//     B: wb[(colBase+wc+jj*32+l31)*512 + kt*128 + kk*64 + h*32 ..+32)
// — byte-identical to what the r7-verified LDS path delivered to the MFMA.
// Eliminates: all __syncthreads, all bank conflicts, staging writes, and
// staging address VALU. 16 independent 32-B loads per kt give deep MLP;
// the compiler emits counted vmcnt interleave. L2 locality is incidental:
// grid.x mod 8 pins each row-block (its 64-KB A panel) to one XCD's L2
// across all 227 column stripes.
// Geometry: r0's proven 128x128 tile, 4 waves 2x2, wave tile 64x64 =
// 2x2 of 32x32 (acc 64). Regs ~150 (acc 64 + aq/bq 64 + ptrs) ->
// launch_bounds(256,3): cap 170, ~3 blocks/CU, 12 free-running waves.
// Bounds: max B row = 226*128+127 = 29055 = VPAD-1 (no clamp needed);
// bias=-1e30 for col>=VOCAB zeroes the pad columns' exp contribution.
__global__ void __launch_bounds__(256, 3)
gemm_stats_kernel(const uint8_t* __restrict__ xb, const uint8_t* __restrict__ wb,
                  const float* __restrict__ bias, float* __restrict__ sg) {
  const int tid  = threadIdx.x;
  const int lane = tid & 63;
  const int w    = tid >> 6;       // wave 0..3
  const int l31  = lane & 31;
  const int h    = lane >> 5;      // k-half for 32x32 operands
  const int wr   = (w >> 1) * 64;  // wave row offset in tile
  const int wc   = (w & 1) * 64;   // wave col offset in tile
  const int rowBase = blockIdx.x * 128;  // x rows     (grid.x = 64)
  const int colBase = blockIdx.y * 128;  // vocab cols (grid.y = 227)

  // per-lane fragment base pointers (h selects the 32-B k-half)
  const uint8_t* pa = xb + (size_t)(rowBase + wr + l31) * EMBED + h * 32;
  const uint8_t* pb = wb + (size_t)(colBase + wc + l31) * EMBED + h * 32;

  f32x16 acc[2][2];
#pragma unroll
  for (int i = 0; i < 2; ++i)
#pragma unroll
    for (int j = 0; j < 2; ++j)
#pragma unroll
      for (int r = 0; r < 16; ++r) acc[i][j][r] = 0.f;

#pragma unroll
  for (int kt = 0; kt < 4; ++kt) {
    const int ko = kt * 128;
    // issue all 16 fragment loads up front (independent -> deep MLP)
    i32x8 bq[2][2], aq[2][2];   // [kk][jj] / [kk][ii]
#pragma unroll
    for (int kk = 0; kk < 2; ++kk)
#pragma unroll
      for (int jj = 0; jj < 2; ++jj)
        bq[kk][jj] = *(const i32x8*)(pb + jj * (32 * EMBED) + ko + kk * 64);
#pragma unroll
    for (int kk = 0; kk < 2; ++kk)
#pragma unroll
      for (int ii = 0; ii < 2; ++ii)
        aq[kk][ii] = *(const i32x8*)(pa + ii * (32 * EMBED) + ko + kk * 64);
#pragma unroll
    for (int kk = 0; kk < 2; ++kk)
#pragma unroll
      for (int ii = 0; ii < 2; ++ii) {
        acc[ii][0] = __builtin_amdgcn_mfma_scale_f32_32x32x64_f8f6f4(
            aq[kk][ii], bq[kk][0], acc[ii][0], 0, 0, 0, 0x7F7F7F7F, 0, 0x7F7F7F7F);
        acc[ii][1] = __builtin_amdgcn_mfma_scale_f32_32x32x64_f8f6f4(
            aq[kk][ii], bq[kk][1], acc[ii][1], 0, 0, 0, 0x7F7F7F7F, 0, 0x7F7F7F7F);
      }
  }

  // ---- epilogue: s_row += sum_j exp(acc/16 + bias)  (r0 verbatim) ----
  // 32x32 C/D layout (m74/m101): col = lane&31, row = (reg&3)+8*(reg>>2)+4*h
  float bvl[2];
#pragma unroll
  for (int jj = 0; jj < 2; ++jj) {
    const int col = colBase + wc + jj * 32 + l31;
    bvl[jj] = (col < VOCAB) ? bias[col] * LOG2E : -1e30f;
  }

  float sp[32];  // v = ii*16 + reg
#pragma unroll
  for (int ii = 0; ii < 2; ++ii)
#pragma unroll
    for (int r = 0; r < 16; ++r)
      sp[ii * 16 + r] = exp2f(fmaf(acc[ii][0][r], INV_WSCALE_L2E, bvl[0])) +
                        exp2f(fmaf(acc[ii][1][r], INV_WSCALE_L2E, bvl[1]));

  // stacking reduction over the 32 cols (xor 1..16 stays within the h-half);
  // ends with lane holding the full col-sum for value index v == (lane&31).
  float t1[16];
#pragma unroll
  for (int u = 0; u < 16; ++u) {
    float a = sp[2 * u]     + __shfl_xor(sp[2 * u],     1);
    float b = sp[2 * u + 1] + __shfl_xor(sp[2 * u + 1], 1);
    t1[u] = (l31 & 1) ? b : a;
  }
  float t2[8];
#pragma unroll
  for (int u = 0; u < 8; ++u) {
    float a = t1[2 * u]     + __shfl_xor(t1[2 * u],     2);
    float b = t1[2 * u + 1] + __shfl_xor(t1[2 * u + 1], 2);
    t2[u] = (l31 & 2) ? b : a;
  }
  float t3[4];
#pragma unroll
  for (int u = 0; u < 4; ++u) {
    float a = t2[2 * u]     + __shfl_xor(t2[2 * u],     4);
    float b = t2[2 * u + 1] + __shfl_xor(t2[2 * u + 1], 4);
    t3[u] = (l31 & 4) ? b : a;
  }
  float t4[2];
#pragma unroll
  for (int u = 0; u < 2; ++u) {
    float a = t3[2 * u]     + __shfl_xor(t3[2 * u],     8);
    float b = t3[2 * u + 1] + __shfl_xor(t3[2 * u + 1], 8);
    t4[u] = (l31 & 8) ? b : a;
  }
  {
    float a = t4[0] + __shfl_xor(t4[0], 16);
    float b = t4[1] + __shfl_xor(t4[1], 16);
    float ssum = (l31 & 16) ? b : a;
    const int v = l31;                 // ii = v>>4, reg = v&15
    const int row = rowBase + wr + (v >> 4) * 32 + (v & 3) + 8 * ((v & 15) >> 2) + 4 * h;
    atomicAdd(&sg[row], ssum);
  }
}

// ---- final: loss = log(V+1) - mean(py/s)  (q-term ~7e-10, dropped) ----
// widened to 1024 threads (was a 1-block/256-thread latency tail)
__global__ void __launch_bounds__(1024)
finalize_kernel(const float* __restrict__ sg, const float* __restrict__ py,
                float* __restrict__ out) {
  __shared__ float red[1024];
  float a = 0.f;
  for (int i = threadIdx.x; i < NROWS; i += 1024)
    a += py[i] / sg[i];
  red[threadIdx.x] = a;
  __syncthreads();
  for (int st = 512; st > 0; st >>= 1) {
    if (threadIdx.x < st) red[threadIdx.x] += red[threadIdx.x + st];
    __syncthreads();
  }
  if (threadIdx.x == 0)
    out[0] = logf((float)(VOCAB + 1)) - red[0] * (1.f / (float)NROWS);
}

extern "C" void kernel_launch(void* const* d_in, const int* in_sizes, int n_in,
                              void* d_out, int out_size, void* d_ws, size_t ws_size,
                              hipStream_t stream) {
  const float* x = (const float*)d_in[0];
  const int*   y = (const int*)d_in[1];
  const float* W = (const float*)d_in[2];
  const float* b = (const float*)d_in[3];

  char* ws = (char*)d_ws;
  uint8_t* xb = (uint8_t*)ws;                             // 4,194,304 B
  uint8_t* wb = (uint8_t*)(ws + 4194304);                 // 14,876,672 B
  float*   sg = (float*)(ws + 4194304 + 14876672);        // 32 KiB
  float*   py = sg + NROWS;                               // 32 KiB

  prep_kernel<<<11392, 256, 0, stream>>>(x, W, b, y, (int*)xb, (int*)wb, py, sg);
  gemm_stats_kernel<<<dim3(64, 227), 256, 0, stream>>>(xb, wb, b, sg);
  finalize_kernel<<<1, 1024, 0, stream>>>(sg, py, (float*)d_out);
}

// Round 10
// 324.822 us; speedup vs baseline: 1.5966x; 1.5966x over previous
//
#include <hip/hip_runtime.h>
#include <stdint.h>

#define VOCAB 28996
#define EMBED 512
#define NROWS 8192
#define VPAD  29056  /* 227 * 128 */
#define LOG2E 1.4426950408889634f
#define WSCALE 16.0f
#define INV_WSCALE_L2E (LOG2E / 16.0f)

typedef __attribute__((ext_vector_type(4)))  int   i32x4;
typedef __attribute__((ext_vector_type(8)))  int   i32x8;
typedef __attribute__((ext_vector_type(16))) float f32x16;

__device__ __forceinline__ void gload_lds16(const void* g, void* l) {
  __builtin_amdgcn_global_load_lds(
      (__attribute__((address_space(1))) const void*)g,
      (__attribute__((address_space(3))) void*)l, 16, 0, 0);
}

// pack 4 floats -> 4 x fp8 e4m3 (OCP, RNE, saturating) in one i32
__device__ __forceinline__ int pk_fp8x4(float a, float b, float c, float d) {
  int r = __builtin_amdgcn_cvt_pk_fp8_f32(a, b, 0, false);
  r = __builtin_amdgcn_cvt_pk_fp8_f32(c, d, r, true);
  return r;
}

// ---- fused prep (IDENTICAL to the harness-verified round-0 kernel) ----
// blocks [0,7264): W   (VPAD*512/8/256 = 7264)
// blocks [7264,9312): x (8192*512/8/256 = 2048)
// blocks [9312,11360): py (1 wave/row, 4 rows/block)
// blocks [11360,11392): zero sg
__global__ void __launch_bounds__(256)
prep_kernel(const float* __restrict__ x, const float* __restrict__ W,
            const float* __restrict__ b, const int* __restrict__ y,
            int* __restrict__ xb, int* __restrict__ wb,
            float* __restrict__ py, float* __restrict__ sg) {
  const int bid = blockIdx.x;
  if (bid < 7264) {                        // ---- cvt W*16 -> fp8 ----
    int i = (bid * 256 + threadIdx.x) * 8; // float index; VK multiple of 8
    const int VK = VOCAB * EMBED;
    int2 o;
    if (i < VK) {
      float4 v0 = *(const float4*)(W + i);
      float4 v1 = *(const float4*)(W + i + 4);
      o.x = pk_fp8x4(v0.x * WSCALE, v0.y * WSCALE, v0.z * WSCALE, v0.w * WSCALE);
      o.y = pk_fp8x4(v1.x * WSCALE, v1.y * WSCALE, v1.z * WSCALE, v1.w * WSCALE);
    } else { o.x = 0; o.y = 0; }
    *(int2*)(wb + i / 4) = o;
  } else if (bid < 9312) {                 // ---- cvt x -> fp8 ----
    int i = ((bid - 7264) * 256 + threadIdx.x) * 8;
    float4 v0 = *(const float4*)(x + i);
    float4 v1 = *(const float4*)(x + i + 4);
    int2 o;
    o.x = pk_fp8x4(v0.x, v0.y, v0.z, v0.w);
    o.y = pk_fp8x4(v1.x, v1.y, v1.z, v1.w);
    *(int2*)(xb + i / 4) = o;
  } else if (bid < 11360) {                // ---- py: e^{x.W[y]+b[y]}, fp32 exact ----
    const int row  = ((bid - 9312) * 256 + threadIdx.x) >> 6;
    const int lane = threadIdx.x & 63;
    const int yr = y[row];
    const float4* xr = (const float4*)(x + (size_t)row * EMBED);
    const float4* wr = (const float4*)(W + (size_t)yr * EMBED);
    float d = 0.f;
#pragma unroll
    for (int t = 0; t < 2; ++t) {
      float4 a = xr[lane * 2 + t], c = wr[lane * 2 + t];
      d += a.x * c.x + a.y * c.y + a.z * c.z + a.w * c.w;
    }
#pragma unroll
    for (int m = 1; m < 64; m <<= 1) d += __shfl_xor(d, m);
    if (lane == 0) py[row] = __expf(d + b[yr]);
  } else {                                 // ---- zero sg ----
    int i = (bid - 11360) * 256 + threadIdx.x;
    sg[i] = 0.f;
  }
}

// ---- fused GEMM (16*logits = x . (16W)^T, MX-fp8 32x32x64) + row-sum exp ----
// Round-10 = round-0 (proven 176 us: 128x128 tile, 4 waves 2x2, BK=128,
// single buffer, 2-sync schedule, grid 64x227, launch_bounds(256,4))
// with ONE change: K-MAJOR LDS CHUNK LAYOUT to kill the measured 4-way
// fragment-read bank conflict (SQ_LDS_BANK_CONFLICT = 1.49e7 = 4 cy per
// ds_read_b128 = ~24 us of the 176).
//   Chunk = 8 rows x 128 B (1024 B). NEW offset-in-chunk = J*128 + r*16
//   (J = 16-B k-slot 0..7, r = row&7) instead of row-major r*128 + swz(J)*16.
//   Fragment reads then walk ascending 16-B steps (bank = 4*(lane&7),
//   ascending) — the lane->bank map of a LINEAR read, which is the
//   measured conflict-free pattern (m134). Row-stride-128 patterns (any
//   XOR swizzle, r0 incl.) stay in the 4-way class; this leaves the class.
// Staging: global_load_lds dest stays linear (chunk base + lane*16, HW
// requirement); only the per-lane GLOBAL source is permuted: lane L stages
// row c*8+(L&7), k-slot (L>>3) — same 8x128-B footprint per instruction,
// so global coalescing is unchanged. Delivered fragment bytes are
// bit-identical to r0's verified operands.
// Also: fragment addresses become base-vreg + immediate offsets (the old
// per-kk XOR address VALU disappears).
__global__ void __launch_bounds__(256, 4)
gemm_stats_kernel(const uint8_t* __restrict__ xb, const uint8_t* __restrict__ wb,
                  const float* __restrict__ bias, float* __restrict__ sg) {
  __shared__ uint8_t lA[128 * 128];
  __shared__ uint8_t lB[128 * 128];

  const int tid  = threadIdx.x;
  const int lane = tid & 63;
  const int w    = tid >> 6;       // wave 0..3
  const int l31  = lane & 31;
  const int h    = lane >> 5;      // k-half for 32x32 operands
  const int wr   = (w >> 1) * 64;  // wave row offset in tile
  const int wc   = (w & 1) * 64;   // wave col offset in tile
  const int rowBase = blockIdx.x * 128;  // x rows     (grid.x = 64)
  const int colBase = blockIdx.y * 128;  // vocab cols (grid.y = 227)

  // staging lane mapping (K-major): lane L covers row c*8+(L&7), slot L>>3
  const int srcRow = lane & 7;           // row within 8-row chunk
  const int srcSlt = (lane >> 3) * 16;   // 16-B k-slot byte offset

  f32x16 acc[2][2];
#pragma unroll
  for (int i = 0; i < 2; ++i)
#pragma unroll
    for (int j = 0; j < 2; ++j)
#pragma unroll
      for (int r = 0; r < 16; ++r) acc[i][j][r] = 0.f;

  auto stage = [&](int k0) {
#pragma unroll
    for (int t = 0; t < 4; ++t) {
      const int c = w * 4 + t;               // chunk 0..15 (8 rows each)
      gload_lds16(xb + (size_t)(rowBase + c * 8 + srcRow) * EMBED + k0 + srcSlt,
                  &lA[c * 1024]);
      gload_lds16(wb + (size_t)(colBase + c * 8 + srcRow) * EMBED + k0 + srcSlt,
                  &lB[c * 1024]);
    }
  };

  // fragment read base: operand row (block + l31) lives in chunk
  // block/8 + (l31>>3) at row-minor (l31&7)*16; k-slot J adds J*128.
  const int rsel  = (l31 >> 3) * 1024 + (l31 & 7) * 16;
  const int aBase = wr * 128 + rsel;       // + ii*4096 + J*128 (+128 for hi)
  const int bBase = wc * 128 + rsel;       // + jj*4096 + J*128

#pragma unroll
  for (int kt = 0; kt < 4; ++kt) {
    stage(kt * 128);
    __syncthreads();                       // vmcnt(0)+lgkmcnt(0)+barrier
#pragma unroll
    for (int kk = 0; kk < 2; ++kk) {
      const int off = (kk * 4 + h * 2) * 128;   // J*128, J = kk*4+h*2
      i32x8 bq[2];
#pragma unroll
      for (int jj = 0; jj < 2; ++jj) {
        const uint8_t* bp = &lB[bBase + jj * 4096 + off];
        i32x4 lo = *(const i32x4*)(bp);
        i32x4 hi = *(const i32x4*)(bp + 128);
        bq[jj] = __builtin_shufflevector(lo, hi, 0, 1, 2, 3, 4, 5, 6, 7);
      }
#pragma unroll
      for (int ii = 0; ii < 2; ++ii) {
        const uint8_t* ap = &lA[aBase + ii * 4096 + off];
        i32x4 lo = *(const i32x4*)(ap);
        i32x4 hi = *(const i32x4*)(ap + 128);
        i32x8 af = __builtin_shufflevector(lo, hi, 0, 1, 2, 3, 4, 5, 6, 7);
        acc[ii][0] = __builtin_amdgcn_mfma_scale_f32_32x32x64_f8f6f4(
            af, bq[0], acc[ii][0], 0, 0, 0, 0x7F7F7F7F, 0, 0x7F7F7F7F);
        acc[ii][1] = __builtin_amdgcn_mfma_scale_f32_32x32x64_f8f6f4(
            af, bq[1], acc[ii][1], 0, 0, 0, 0x7F7F7F7F, 0, 0x7F7F7F7F);
      }
    }
    __syncthreads();                       // protect buffer reuse (single buf)
  }

  // ---- epilogue: s_row += sum_j exp(acc/16 + bias)  (r0 verbatim) ----
  // 32x32 C/D layout (m74/m101): col = lane&31, row = (reg&3)+8*(reg>>2)+4*h
  float bvl[2];
#pragma unroll
  for (int jj = 0; jj < 2; ++jj) {
    const int col = colBase + wc + jj * 32 + l31;
    bvl[jj] = (col < VOCAB) ? bias[col] * LOG2E : -1e30f;
  }

  float sp[32];  // v = ii*16 + reg
#pragma unroll
  for (int ii = 0; ii < 2; ++ii)
#pragma unroll
    for (int r = 0; r < 16; ++r)
      sp[ii * 16 + r] = exp2f(fmaf(acc[ii][0][r], INV_WSCALE_L2E, bvl[0])) +
                        exp2f(fmaf(acc[ii][1][r], INV_WSCALE_L2E, bvl[1]));

  // stacking reduction over the 32 cols (xor 1..16 stays within the h-half);
  // ends with lane holding the full col-sum for value index v == (lane&31).
  float t1[16];
#pragma unroll
  for (int u = 0; u < 16; ++u) {
    float a = sp[2 * u]     + __shfl_xor(sp[2 * u],     1);
    float b = sp[2 * u + 1] + __shfl_xor(sp[2 * u + 1], 1);
    t1[u] = (l31 & 1) ? b : a;
  }
  float t2[8];
#pragma unroll
  for (int u = 0; u < 8; ++u) {
    float a = t1[2 * u]     + __shfl_xor(t1[2 * u],     2);
    float b = t1[2 * u + 1] + __shfl_xor(t1[2 * u + 1], 2);
    t2[u] = (l31 & 2) ? b : a;
  }
  float t3[4];
#pragma unroll
  for (int u = 0; u < 4; ++u) {
    float a = t2[2 * u]     + __shfl_xor(t2[2 * u],     4);
    float b = t2[2 * u + 1] + __shfl_xor(t2[2 * u + 1], 4);
    t3[u] = (l31 & 4) ? b : a;
  }
  float t4[2];
#pragma unroll
  for (int u = 0; u < 2; ++u) {
    float a = t3[2 * u]     + __shfl_xor(t3[2 * u],     8);
    float b = t3[2 * u + 1] + __shfl_xor(t3[2 * u + 1], 8);
    t4[u] = (l31 & 8) ? b : a;
  }
  {
    float a = t4[0] + __shfl_xor(t4[0], 16);
    float b = t4[1] + __shfl_xor(t4[1], 16);
    float ssum = (l31 & 16) ? b : a;
    const int v = l31;                 // ii = v>>4, reg = v&15
    const int row = rowBase + wr + (v >> 4) * 32 + (v & 3) + 8 * ((v & 15) >> 2) + 4 * h;
    atomicAdd(&sg[row], ssum);
  }
}

// ---- final: loss = log(V+1) - mean(py/s)  (q-term ~7e-10, dropped) ----
// 1024 threads (ran clean in round 9)
__global__ void __launch_bounds__(1024)
finalize_kernel(const float* __restrict__ sg, const float* __restrict__ py,
                float* __restrict__ out) {
  __shared__ float red[1024];
  float a = 0.f;
  for (int i = threadIdx.x; i < NROWS; i += 1024)
    a += py[i] / sg[i];
  red[threadIdx.x] = a;
  __syncthreads();
  for (int st = 512; st > 0; st >>= 1) {
    if (threadIdx.x < st) red[threadIdx.x] += red[threadIdx.x + st];
    __syncthreads();
  }
  if (threadIdx.x == 0)
    out[0] = logf((float)(VOCAB + 1)) - red[0] * (1.f / (float)NROWS);
}

extern "C" void kernel_launch(void* const* d_in, const int* in_sizes, int n_in,
                              void* d_out, int out_size, void* d_ws, size_t ws_size,
                              hipStream_t stream) {
  const float* x = (const float*)d_in[0];
  const int*   y = (const int*)d_in[1];
  const float* W = (const float*)d_in[2];
  const float* b = (const float*)d_in[3];

  char* ws = (char*)d_ws;
  uint8_t* xb = (uint8_t*)ws;                             // 4,194,304 B
  uint8_t* wb = (uint8_t*)(ws + 4194304);                 // 14,876,672 B
  float*   sg = (float*)(ws + 4194304 + 14876672);        // 32 KiB
  float*   py = sg + NROWS;                               // 32 KiB

  prep_kernel<<<11392, 256, 0, stream>>>(x, W, b, y, (int*)xb, (int*)wb, py, sg);
  gemm_stats_kernel<<<dim3(64, 227), 256, 0, stream>>>(xb, wb, b, sg);
  finalize_kernel<<<1, 1024, 0, stream>>>(sg, py, (float*)d_out);
}

// Round 11
// 280.268 us; speedup vs baseline: 1.8504x; 1.1590x over previous
//
#include <hip/hip_runtime.h>
#include <stdint.h>

#define VOCAB 28996
#define EMBED 512
#define NROWS 8192
#define VPAD  29056  /* 227 * 128 */
#define LOG2E 1.4426950408889634f
#define WSCALE 16.0f
#define INV_WSCALE_L2E (LOG2E / 16.0f)

typedef __attribute__((ext_vector_type(4)))  int   i32x4;
typedef __attribute__((ext_vector_type(8)))  int   i32x8;
typedef __attribute__((ext_vector_type(16))) float f32x16;

__device__ __forceinline__ void gload_lds16(const void* g, void* l) {
  __builtin_amdgcn_global_load_lds(
      (__attribute__((address_space(1))) const void*)g,
      (__attribute__((address_space(3))) void*)l, 16, 0, 0);
}

// pack 4 floats -> 4 x fp8 e4m3 (OCP, RNE, saturating) in one i32
__device__ __forceinline__ int pk_fp8x4(float a, float b, float c, float d) {
  int r = __builtin_amdgcn_cvt_pk_fp8_f32(a, b, 0, false);
  r = __builtin_amdgcn_cvt_pk_fp8_f32(c, d, r, true);
  return r;
}

__device__ __forceinline__ int pk_fp8x4v(float4 v, float s) {
  return pk_fp8x4(v.x * s, v.y * s, v.z * s, v.w * s);
}

// ---- fused prep, RESTRUCTURED for bandwidth (round 11) ----
// r0's prep left ~75-90 us of non-gemm time (~3x the 22 us traffic roofline).
// Changes: (1) py (random W-row gather, latency-bound) moved FIRST so it
// hides under the streaming W-cvt instead of tail-ending the kernel;
// (2) W/x cvt widened to 16 floats/thread: 4 float4 loads in flight +
// single int4 (16-B) store — was 2 loads + int2 (8-B) store.
// Same math, same outputs, same workspace layout as the verified r0 prep.
// blocks [0,2048):    py  (1 wave/row, 4 rows/block)
// blocks [2048,5680): W*16 -> fp8, pad to VPAD  (VPAD*512/16/256 = 3632)
// blocks [5680,6704): x -> fp8                  (8192*512/16/256 = 1024)
// blocks [6704,6736): zero sg
__global__ void __launch_bounds__(256)
prep_kernel(const float* __restrict__ x, const float* __restrict__ W,
            const float* __restrict__ b, const int* __restrict__ y,
            int* __restrict__ xb, int* __restrict__ wb,
            float* __restrict__ py, float* __restrict__ sg) {
  const int bid = blockIdx.x;
  if (bid < 2048) {                        // ---- py: e^{x.W[y]+b[y]}, fp32 exact ----
    const int row  = (bid * 256 + threadIdx.x) >> 6;
    const int lane = threadIdx.x & 63;
    const int yr = y[row];
    const float4* xr = (const float4*)(x + (size_t)row * EMBED);
    const float4* wr = (const float4*)(W + (size_t)yr * EMBED);
    float d = 0.f;
#pragma unroll
    for (int t = 0; t < 2; ++t) {
      float4 a = xr[lane * 2 + t], c = wr[lane * 2 + t];
      d += a.x * c.x + a.y * c.y + a.z * c.z + a.w * c.w;
    }
#pragma unroll
    for (int m = 1; m < 64; m <<= 1) d += __shfl_xor(d, m);
    if (lane == 0) py[row] = __expf(d + b[yr]);
  } else if (bid < 5680) {                 // ---- cvt W*16 -> fp8 (16/thread) ----
    int i = ((bid - 2048) * 256 + threadIdx.x) * 16;  // float index
    const int VK = VOCAB * EMBED;                     // multiple of 16
    int4 o;
    if (i < VK) {
      const float4* p = (const float4*)(W + i);
      o.x = pk_fp8x4v(p[0], WSCALE);
      o.y = pk_fp8x4v(p[1], WSCALE);
      o.z = pk_fp8x4v(p[2], WSCALE);
      o.w = pk_fp8x4v(p[3], WSCALE);
    } else { o.x = 0; o.y = 0; o.z = 0; o.w = 0; }
    *(int4*)(wb + i / 4) = o;
  } else if (bid < 6704) {                 // ---- cvt x -> fp8 (16/thread) ----
    int i = ((bid - 5680) * 256 + threadIdx.x) * 16;
    const float4* p = (const float4*)(x + i);
    int4 o;
    o.x = pk_fp8x4v(p[0], 1.f);
    o.y = pk_fp8x4v(p[1], 1.f);
    o.z = pk_fp8x4v(p[2], 1.f);
    o.w = pk_fp8x4v(p[3], 1.f);
    *(int4*)(xb + i / 4) = o;
  } else {                                 // ---- zero sg ----
    int i = (bid - 6704) * 256 + threadIdx.x;
    sg[i] = 0.f;
  }
}

// ---- fused GEMM (16*logits = x . (16W)^T, MX-fp8 32x32x64) + row-sum exp ----
// ROUND-0 VERBATIM (proven 176 us; best of 9 structural variants this
// session). 128x128 tile, BK=128 staged; 4 waves 2x2, each wave 64x64 =
// 2x2 of 32x32. launch_bounds(256,4) -> 64 VGPR + 64 AGPR acc, no spill,
// ~3.3 blocks/CU. LDS row = 128 B; 16B-chunk XOR swizzle (chunk J of row R
// at LDS[R*128 + ((J^(R&7))*16)]) — staging contiguous for global_load_lds,
// fragment reads conflict-free (r10 experiment proved SQ_LDS_BANK_CONFLICT
// = staging-write burst serialization, 8 cy/gload_lds, a BW floor — not a
// read conflict).
__global__ void __launch_bounds__(256, 4)
gemm_stats_kernel(const uint8_t* __restrict__ xb, const uint8_t* __restrict__ wb,
                  const float* __restrict__ bias, float* __restrict__ sg) {
  __shared__ uint8_t lA[128 * 128];
  __shared__ uint8_t lB[128 * 128];

  const int tid  = threadIdx.x;
  const int lane = tid & 63;
  const int w    = tid >> 6;       // wave 0..3
  const int l31  = lane & 31;
  const int h    = lane >> 5;      // k-half for 32x32 operands
  const int kx   = lane & 7;       // swizzle key (fragment row & 7 == lane & 7)
  const int wr   = (w >> 1) * 64;  // wave row offset in tile
  const int wc   = (w & 1) * 64;   // wave col offset in tile
  const int rowBase = blockIdx.x * 128;  // x rows (grid.x = 64)
  const int colBase = blockIdx.y * 128;  // vocab cols (grid.y = 227)

  f32x16 acc[2][2];
#pragma unroll
  for (int i = 0; i < 2; ++i)
#pragma unroll
    for (int j = 0; j < 2; ++j)
#pragma unroll
      for (int r = 0; r < 16; ++r) acc[i][j][r] = 0.f;

  const int srow = lane >> 3;                    // 0..7 (row within 8-row chunk)
  const int skel = ((lane & 7) ^ srow) * 16;     // swizzled byte offset in row

  const int aBase = (wr + l31) * 128;            // ii=0 fragment row base
  const int bBase = (wc + l31) * 128;            // jj=0 fragment row base

  for (int kt = 0; kt < 4; ++kt) {
    const int k0 = kt * 128;                     // byte offset in 512B row
#pragma unroll
    for (int t = 0; t < 4; ++t) {
      const int c = w * 4 + t;                   // chunk 0..15 (8 rows each)
      const int r = c * 8 + srow;                // tile row 0..127
      gload_lds16(xb + (size_t)(rowBase + r) * EMBED + k0 + skel, &lA[c * 1024]);
      gload_lds16(wb + (size_t)(colBase + r) * EMBED + k0 + skel, &lB[c * 1024]);
    }
    __syncthreads();
#pragma unroll
    for (int kk = 0; kk < 2; ++kk) {
      // lane's 32 k-bytes: chunks J0, J0+1 where J0 = kk*4 + h*2 (even)
      const int c0 = ((kk * 4 + h * 2) ^ kx) << 4;
      const int c1 = c0 ^ 16;                    // ((J0|1)^kx)*16
      i32x8 bq[2];
#pragma unroll
      for (int jj = 0; jj < 2; ++jj) {
        const int base = bBase + jj * 32 * 128;
        i32x4 lo = *(const i32x4*)&lB[base + c0];
        i32x4 hi = *(const i32x4*)&lB[base + c1];
        bq[jj] = __builtin_shufflevector(lo, hi, 0, 1, 2, 3, 4, 5, 6, 7);
      }
#pragma unroll
      for (int ii = 0; ii < 2; ++ii) {
        const int base = aBase + ii * 32 * 128;
        i32x4 lo = *(const i32x4*)&lA[base + c0];
        i32x4 hi = *(const i32x4*)&lA[base + c1];
        i32x8 af = __builtin_shufflevector(lo, hi, 0, 1, 2, 3, 4, 5, 6, 7);
        acc[ii][0] = __builtin_amdgcn_mfma_scale_f32_32x32x64_f8f6f4(
            af, bq[0], acc[ii][0], 0, 0, 0, 0x7F7F7F7F, 0, 0x7F7F7F7F);
        acc[ii][1] = __builtin_amdgcn_mfma_scale_f32_32x32x64_f8f6f4(
            af, bq[1], acc[ii][1], 0, 0, 0, 0x7F7F7F7F, 0, 0x7F7F7F7F);
      }
    }
    __syncthreads();
  }

  // ---- epilogue: s_row += sum_j exp(acc/16 + bias) ----
  // 32x32 C/D layout (m74/m101): col = lane&31, row = (reg&3)+8*(reg>>2)+4*h
  float bvl[2];
#pragma unroll
  for (int jj = 0; jj < 2; ++jj) {
    const int col = colBase + wc + jj * 32 + l31;
    bvl[jj] = (col < VOCAB) ? bias[col] * LOG2E : -1e30f;
  }

  float sp[32];  // v = ii*16 + reg
#pragma unroll
  for (int ii = 0; ii < 2; ++ii)
#pragma unroll
    for (int r = 0; r < 16; ++r)
      sp[ii * 16 + r] = exp2f(fmaf(acc[ii][0][r], INV_WSCALE_L2E, bvl[0])) +
                        exp2f(fmaf(acc[ii][1][r], INV_WSCALE_L2E, bvl[1]));

  // stacking reduction over the 32 cols (xor 1..16 stays within the h-half);
  // ends with lane holding the full col-sum for value index v == (lane&31).
  float t1[16];
#pragma unroll
  for (int u = 0; u < 16; ++u) {
    float a = sp[2 * u]     + __shfl_xor(sp[2 * u],     1);
    float b = sp[2 * u + 1] + __shfl_xor(sp[2 * u + 1], 1);
    t1[u] = (l31 & 1) ? b : a;
  }
  float t2[8];
#pragma unroll
  for (int u = 0; u < 8; ++u) {
    float a = t1[2 * u]     + __shfl_xor(t1[2 * u],     2);
    float b = t1[2 * u + 1] + __shfl_xor(t1[2 * u + 1], 2);
    t2[u] = (l31 & 2) ? b : a;
  }
  float t3[4];
#pragma unroll
  for (int u = 0; u < 4; ++u) {
    float a = t2[2 * u]     + __shfl_xor(t2[2 * u],     4);
    float b = t2[2 * u + 1] + __shfl_xor(t2[2 * u + 1], 4);
    t3[u] = (l31 & 4) ? b : a;
  }
  float t4[2];
#pragma unroll
  for (int u = 0; u < 2; ++u) {
    float a = t3[2 * u]     + __shfl_xor(t3[2 * u],     8);
    float b = t3[2 * u + 1] + __shfl_xor(t3[2 * u + 1], 8);
    t4[u] = (l31 & 8) ? b : a;
  }
  {
    float a = t4[0] + __shfl_xor(t4[0], 16);
    float b = t4[1] + __shfl_xor(t4[1], 16);
    float ssum = (l31 & 16) ? b : a;
    const int v = l31;                 // ii = v>>4, reg = v&15
    const int row = rowBase + wr + (v >> 4) * 32 + (v & 3) + 8 * ((v & 15) >> 2) + 4 * h;
    atomicAdd(&sg[row], ssum);
  }
}

// ---- final: loss = log(V+1) - mean(py/s)  (q-term ~7e-10, dropped) ----
__global__ void __launch_bounds__(1024)
finalize_kernel(const float* __restrict__ sg, const float* __restrict__ py,
                float* __restrict__ out) {
  __shared__ float red[1024];
  float a = 0.f;
  for (int i = threadIdx.x; i < NROWS; i += 1024)
    a += py[i] / sg[i];
  red[threadIdx.x] = a;
  __syncthreads();
  for (int st = 512; st > 0; st >>= 1) {
    if (threadIdx.x < st) red[threadIdx.x] += red[threadIdx.x + st];
    __syncthreads();
  }
  if (threadIdx.x == 0)
    out[0] = logf((float)(VOCAB + 1)) - red[0] * (1.f / (float)NROWS);
}

extern "C" void kernel_launch(void* const* d_in, const int* in_sizes, int n_in,
                              void* d_out, int out_size, void* d_ws, size_t ws_size,
                              hipStream_t stream) {
  const float* x = (const float*)d_in[0];
  const int*   y = (const int*)d_in[1];
  const float* W = (const float*)d_in[2];
  const float* b = (const float*)d_in[3];

  char* ws = (char*)d_ws;
  uint8_t* xb = (uint8_t*)ws;                             // 4,194,304 B
  uint8_t* wb = (uint8_t*)(ws + 4194304);                 // 14,876,672 B
  float*   sg = (float*)(ws + 4194304 + 14876672);        // 32 KiB
  float*   py = sg + NROWS;                               // 32 KiB

  prep_kernel<<<6736, 256, 0, stream>>>(x, W, b, y, (int*)xb, (int*)wb, py, sg);
  gemm_stats_kernel<<<dim3(64, 227), 256, 0, stream>>>(xb, wb, b, sg);
  finalize_kernel<<<1, 1024, 0, stream>>>(sg, py, (float*)d_out);
}

// Round 12
// 267.412 us; speedup vs baseline: 1.9394x; 1.0481x over previous
//
#include <hip/hip_runtime.h>
#include <stdint.h>

#define VOCAB 28996
#define EMBED 512
#define NROWS 8192
#define VPAD  29056  /* 227 * 128 */
#define LOG2E 1.4426950408889634f
#define WSCALE 16.0f
#define INV_WSCALE_L2E (LOG2E / 16.0f)

typedef __attribute__((ext_vector_type(8)))  int   i32x8;
typedef __attribute__((ext_vector_type(16))) float f32x16;

// pack 4 floats -> 4 x fp8 e4m3 (OCP, RNE, saturating) in one i32
__device__ __forceinline__ int pk_fp8x4(float a, float b, float c, float d) {
  int r = __builtin_amdgcn_cvt_pk_fp8_f32(a, b, 0, false);
  r = __builtin_amdgcn_cvt_pk_fp8_f32(c, d, r, true);
  return r;
}

__device__ __forceinline__ int pk_fp8x4v(float4 v, float s) {
  return pk_fp8x4(v.x * s, v.y * s, v.z * s, v.w * s);
}

// ---- transposed-fragment address: byte offset of (row r, k) in a buffer
// stored in MFMA-fragment order:
//   rb = r>>5 (32-row block), kb = k>>6 (64-B k-block),
//   lane = ((k>>5)&1)*32 + (r&31), j = k&31
//   addr = (rb*8 + kb)*2048 + lane*32 + j
// A wave's fragment load (fixed rb,kb) = lane*32 -> 2048 contiguous bytes.
__device__ __forceinline__ size_t frag_addr(int r, int k) {
  return ((size_t)((r >> 5) * 8 + (k >> 6)) << 11) +
         ((((k >> 5) & 1) * 32 + (r & 31)) << 5) + (k & 31);
}

// ---- fused prep (round 12): cvt writes FRAGMENT-ORDER xb/wb ----
// Same bytes as before, bijectively permuted so the gemm's per-wave fragment
// loads are fully coalesced (2048B contiguous). Each thread handles 16
// consecutive floats of one row (k..k+16, within one 32-B lane slot) ->
// one int4 store at the transposed address.
// blocks [0,2048):    py  (1 wave/row, 4 rows/block)  [latency; runs first]
// blocks [2048,5680): W*16 -> fp8, pad to VPAD  (VPAD*512/16/256 = 3632)
// blocks [5680,6704): x -> fp8                  (8192*512/16/256 = 1024)
// blocks [6704,6736): zero sg
__global__ void __launch_bounds__(256)
prep_kernel(const float* __restrict__ x, const float* __restrict__ W,
            const float* __restrict__ b, const int* __restrict__ y,
            int* __restrict__ xb, int* __restrict__ wb,
            float* __restrict__ py, float* __restrict__ sg) {
  const int bid = blockIdx.x;
  if (bid < 2048) {                        // ---- py: e^{x.W[y]+b[y]}, fp32 exact ----
    const int row  = (bid * 256 + threadIdx.x) >> 6;
    const int lane = threadIdx.x & 63;
    const int yr = y[row];
    const float4* xr = (const float4*)(x + (size_t)row * EMBED);
    const float4* wr = (const float4*)(W + (size_t)yr * EMBED);
    float d = 0.f;
#pragma unroll
    for (int t = 0; t < 2; ++t) {
      float4 a = xr[lane * 2 + t], c = wr[lane * 2 + t];
      d += a.x * c.x + a.y * c.y + a.z * c.z + a.w * c.w;
    }
#pragma unroll
    for (int m = 1; m < 64; m <<= 1) d += __shfl_xor(d, m);
    if (lane == 0) py[row] = __expf(d + b[yr]);
  } else if (bid < 5680) {                 // ---- cvt W*16 -> fp8, frag order ----
    int i = ((bid - 2048) * 256 + threadIdx.x) * 16;  // float index
    const int VK = VOCAB * EMBED;                     // multiple of 16
    const int r = i >> 9, k = i & 511;
    int4 o;
    if (i < VK) {
      const float4* p = (const float4*)(W + i);
      o.x = pk_fp8x4v(p[0], WSCALE);
      o.y = pk_fp8x4v(p[1], WSCALE);
      o.z = pk_fp8x4v(p[2], WSCALE);
      o.w = pk_fp8x4v(p[3], WSCALE);
    } else { o.x = 0; o.y = 0; o.z = 0; o.w = 0; }
    *(int4*)((uint8_t*)wb + frag_addr(r, k)) = o;
  } else if (bid < 6704) {                 // ---- cvt x -> fp8, frag order ----
    int i = ((bid - 5680) * 256 + threadIdx.x) * 16;
    const int r = i >> 9, k = i & 511;
    const float4* p = (const float4*)(x + i);
    int4 o;
    o.x = pk_fp8x4v(p[0], 1.f);
    o.y = pk_fp8x4v(p[1], 1.f);
    o.z = pk_fp8x4v(p[2], 1.f);
    o.w = pk_fp8x4v(p[3], 1.f);
    *(int4*)((uint8_t*)xb + frag_addr(r, k)) = o;
  } else {                                 // ---- zero sg ----
    int i = (bid - 6704) * 256 + threadIdx.x;
    sg[i] = 0.f;
  }
}

// ---- fused GEMM (16*logits = x . (16W)^T, MX-fp8 32x32x64) + row-sum exp ----
// Round-12: DIRECT-FROM-L2 with FRAGMENT-ORDER operands — no LDS, no
// barriers (r9's proven-correct structure), but every fragment load is now
// a single 2048-B-contiguous coalesced global_load_dwordx8 (16 cache lines
// per instruction vs r9's 64 — r9's failure was TA serialization of the
// 512-B-strided gather, MfmaUtil 11%). The global->fragment transpose that
// r0's LDS performed per-block (14528x) is now done ONCE in prep.
// Geometry: 128x128 tile, 4 waves 2x2, wave tile 64x64 = 2x2 of 32x32
// (acc 64). Free-running waves, deep MLP on 16 independent loads per kt.
// launch_bounds(256,3) (r9 precedent: 68 VGPR, no spill).
// Bounds: cb max = 226*4+3 = 907 < VPAD/32 = 908; bias=-1e30 for
// col>=VOCAB zeroes pad columns' exp contribution.
__global__ void __launch_bounds__(256, 3)
gemm_stats_kernel(const uint8_t* __restrict__ xb, const uint8_t* __restrict__ wb,
                  const float* __restrict__ bias, float* __restrict__ sg) {
  const int tid  = threadIdx.x;
  const int lane = tid & 63;
  const int w    = tid >> 6;       // wave 0..3
  const int l31  = lane & 31;
  const int h    = lane >> 5;      // k-half for 32x32 operands
  const int wr   = (w >> 1) * 64;  // wave row offset in tile
  const int wc   = (w & 1) * 64;   // wave col offset in tile
  const int rowBase = blockIdx.x * 128;  // x rows     (grid.x = 64)
  const int colBase = blockIdx.y * 128;  // vocab cols (grid.y = 227)

  // fragment-order base pointers: 32-row block index * 16384 + lane*32
  const int rbB = blockIdx.x * 4 + (w >> 1) * 2;   // A: rb, rb+1 (ii)
  const int cbB = blockIdx.y * 4 + (w & 1) * 2;    // B: cb, cb+1 (jj)
  const uint8_t* pa = xb + ((size_t)rbB << 14) + lane * 32;
  const uint8_t* pb = wb + ((size_t)cbB << 14) + lane * 32;

  f32x16 acc[2][2];
#pragma unroll
  for (int i = 0; i < 2; ++i)
#pragma unroll
    for (int j = 0; j < 2; ++j)
#pragma unroll
      for (int r = 0; r < 16; ++r) acc[i][j][r] = 0.f;

#pragma unroll
  for (int kt = 0; kt < 4; ++kt) {
    // issue all 16 fragment loads up front (independent -> deep MLP),
    // each 2048B contiguous per wave (perfectly coalesced)
    i32x8 bq[2][2], aq[2][2];   // [kk][jj] / [kk][ii]
#pragma unroll
    for (int kk = 0; kk < 2; ++kk) {
      const size_t off = (size_t)(kt * 2 + kk) << 11;   // kb*2048
#pragma unroll
      for (int jj = 0; jj < 2; ++jj)
        bq[kk][jj] = *(const i32x8*)(pb + ((size_t)jj << 14) + off);
#pragma unroll
      for (int ii = 0; ii < 2; ++ii)
        aq[kk][ii] = *(const i32x8*)(pa + ((size_t)ii << 14) + off);
    }
#pragma unroll
    for (int kk = 0; kk < 2; ++kk)
#pragma unroll
      for (int ii = 0; ii < 2; ++ii) {
        acc[ii][0] = __builtin_amdgcn_mfma_scale_f32_32x32x64_f8f6f4(
            aq[kk][ii], bq[kk][0], acc[ii][0], 0, 0, 0, 0x7F7F7F7F, 0, 0x7F7F7F7F);
        acc[ii][1] = __builtin_amdgcn_mfma_scale_f32_32x32x64_f8f6f4(
            aq[kk][ii], bq[kk][1], acc[ii][1], 0, 0, 0, 0x7F7F7F7F, 0, 0x7F7F7F7F);
      }
  }

  // ---- epilogue: s_row += sum_j exp(acc/16 + bias)  (r9-verified verbatim) ----
  // 32x32 C/D layout (m74/m101): col = lane&31, row = (reg&3)+8*(reg>>2)+4*h
  float bvl[2];
#pragma unroll
  for (int jj = 0; jj < 2; ++jj) {
    const int col = colBase + wc + jj * 32 + l31;
    bvl[jj] = (col < VOCAB) ? bias[col] * LOG2E : -1e30f;
  }

  float sp[32];  // v = ii*16 + reg
#pragma unroll
  for (int ii = 0; ii < 2; ++ii)
#pragma unroll
    for (int r = 0; r < 16; ++r)
      sp[ii * 16 + r] = exp2f(fmaf(acc[ii][0][r], INV_WSCALE_L2E, bvl[0])) +
                        exp2f(fmaf(acc[ii][1][r], INV_WSCALE_L2E, bvl[1]));

  // stacking reduction over the 32 cols (xor 1..16 stays within the h-half);
  // ends with lane holding the full col-sum for value index v == (lane&31).
  float t1[16];
#pragma unroll
  for (int u = 0; u < 16; ++u) {
    float a = sp[2 * u]     + __shfl_xor(sp[2 * u],     1);
    float b = sp[2 * u + 1] + __shfl_xor(sp[2 * u + 1], 1);
    t1[u] = (l31 & 1) ? b : a;
  }
  float t2[8];
#pragma unroll
  for (int u = 0; u < 8; ++u) {
    float a = t1[2 * u]     + __shfl_xor(t1[2 * u],     2);
    float b = t1[2 * u + 1] + __shfl_xor(t1[2 * u + 1], 2);
    t2[u] = (l31 & 2) ? b : a;
  }
  float t3[4];
#pragma unroll
  for (int u = 0; u < 4; ++u) {
    float a = t2[2 * u]     + __shfl_xor(t2[2 * u],     4);
    float b = t2[2 * u + 1] + __shfl_xor(t2[2 * u + 1], 4);
    t3[u] = (l31 & 4) ? b : a;
  }
  float t4[2];
#pragma unroll
  for (int u = 0; u < 2; ++u) {
    float a = t3[2 * u]     + __shfl_xor(t3[2 * u],     8);
    float b = t3[2 * u + 1] + __shfl_xor(t3[2 * u + 1], 8);
    t4[u] = (l31 & 8) ? b : a;
  }
  {
    float a = t4[0] + __shfl_xor(t4[0], 16);
    float b = t4[1] + __shfl_xor(t4[1], 16);
    float ssum = (l31 & 16) ? b : a;
    const int v = l31;                 // ii = v>>4, reg = v&15
    const int row = rowBase + wr + (v >> 4) * 32 + (v & 3) + 8 * ((v & 15) >> 2) + 4 * h;
    atomicAdd(&sg[row], ssum);
  }
}

// ---- final: loss = log(V+1) - mean(py/s)  (q-term ~7e-10, dropped) ----
__global__ void __launch_bounds__(1024)
finalize_kernel(const float* __restrict__ sg, const float* __restrict__ py,
                float* __restrict__ out) {
  __shared__ float red[1024];
  float a = 0.f;
  for (int i = threadIdx.x; i < NROWS; i += 1024)
    a += py[i] / sg[i];
  red[threadIdx.x] = a;
  __syncthreads();
  for (int st = 512; st > 0; st >>= 1) {
    if (threadIdx.x < st) red[threadIdx.x] += red[threadIdx.x + st];
    __syncthreads();
  }
  if (threadIdx.x == 0)
    out[0] = logf((float)(VOCAB + 1)) - red[0] * (1.f / (float)NROWS);
}

extern "C" void kernel_launch(void* const* d_in, const int* in_sizes, int n_in,
                              void* d_out, int out_size, void* d_ws, size_t ws_size,
                              hipStream_t stream) {
  const float* x = (const float*)d_in[0];
  const int*   y = (const int*)d_in[1];
  const float* W = (const float*)d_in[2];
  const float* b = (const float*)d_in[3];

  char* ws = (char*)d_ws;
  uint8_t* xb = (uint8_t*)ws;                             // 4,194,304 B (frag order)
  uint8_t* wb = (uint8_t*)(ws + 4194304);                 // 14,876,672 B (frag order)
  float*   sg = (float*)(ws + 4194304 + 14876672);        // 32 KiB
  float*   py = sg + NROWS;                               // 32 KiB

  prep_kernel<<<6736, 256, 0, stream>>>(x, W, b, y, (int*)xb, (int*)wb, py, sg);
  gemm_stats_kernel<<<dim3(64, 227), 256, 0, stream>>>(xb, wb, b, sg);
  finalize_kernel<<<1, 1024, 0, stream>>>(sg, py, (float*)d_out);
}

// Round 13
// 265.676 us; speedup vs baseline: 1.9520x; 1.0065x over previous
//
#include <hip/hip_runtime.h>
#include <stdint.h>

#define VOCAB 28996
#define EMBED 512
#define NROWS 8192
#define VPAD  29056  /* 227 * 128 */
#define LOG2E 1.4426950408889634f
#define WSCALE 16.0f
#define INV_WSCALE_L2E (LOG2E / 16.0f)

typedef __attribute__((ext_vector_type(8)))  int   i32x8;
typedef __attribute__((ext_vector_type(16))) float f32x16;

// pack 4 floats -> 4 x fp8 e4m3 (OCP, RNE, saturating) in one i32
__device__ __forceinline__ int pk_fp8x4(float a, float b, float c, float d) {
  int r = __builtin_amdgcn_cvt_pk_fp8_f32(a, b, 0, false);
  r = __builtin_amdgcn_cvt_pk_fp8_f32(c, d, r, true);
  return r;
}

__device__ __forceinline__ int pk_fp8x4v(float4 v, float s) {
  return pk_fp8x4(v.x * s, v.y * s, v.z * s, v.w * s);
}

// ---- transposed-fragment address: byte offset of (row r, k) in a buffer
// stored in MFMA-fragment order:
//   rb = r>>5 (32-row block), kb = k>>6 (64-B k-block),
//   lane = ((k>>5)&1)*32 + (r&31), j = k&31
//   addr = (rb*8 + kb)*2048 + lane*32 + j
// A wave's fragment load (fixed rb,kb) = lane*32 -> 2048 contiguous bytes.
__device__ __forceinline__ size_t frag_addr(int r, int k) {
  return ((size_t)((r >> 5) * 8 + (k >> 6)) << 11) +
         ((((k >> 5) & 1) * 32 + (r & 31)) << 5) + (k & 31);
}

// ---- fused prep (r12-verified): cvt writes FRAGMENT-ORDER xb/wb ----
// blocks [0,2048):    py  (1 wave/row, 4 rows/block)  [latency; runs first]
// blocks [2048,5680): W*16 -> fp8, pad to VPAD  (VPAD*512/16/256 = 3632)
// blocks [5680,6704): x -> fp8                  (8192*512/16/256 = 1024)
// blocks [6704,6736): zero sg
__global__ void __launch_bounds__(256)
prep_kernel(const float* __restrict__ x, const float* __restrict__ W,
            const float* __restrict__ b, const int* __restrict__ y,
            int* __restrict__ xb, int* __restrict__ wb,
            float* __restrict__ py, float* __restrict__ sg) {
  const int bid = blockIdx.x;
  if (bid < 2048) {                        // ---- py: e^{x.W[y]+b[y]}, fp32 exact ----
    const int row  = (bid * 256 + threadIdx.x) >> 6;
    const int lane = threadIdx.x & 63;
    const int yr = y[row];
    const float4* xr = (const float4*)(x + (size_t)row * EMBED);
    const float4* wr = (const float4*)(W + (size_t)yr * EMBED);
    float d = 0.f;
#pragma unroll
    for (int t = 0; t < 2; ++t) {
      float4 a = xr[lane * 2 + t], c = wr[lane * 2 + t];
      d += a.x * c.x + a.y * c.y + a.z * c.z + a.w * c.w;
    }
#pragma unroll
    for (int m = 1; m < 64; m <<= 1) d += __shfl_xor(d, m);
    if (lane == 0) py[row] = __expf(d + b[yr]);
  } else if (bid < 5680) {                 // ---- cvt W*16 -> fp8, frag order ----
    int i = ((bid - 2048) * 256 + threadIdx.x) * 16;  // float index
    const int VK = VOCAB * EMBED;                     // multiple of 16
    const int r = i >> 9, k = i & 511;
    int4 o;
    if (i < VK) {
      const float4* p = (const float4*)(W + i);
      o.x = pk_fp8x4v(p[0], WSCALE);
      o.y = pk_fp8x4v(p[1], WSCALE);
      o.z = pk_fp8x4v(p[2], WSCALE);
      o.w = pk_fp8x4v(p[3], WSCALE);
    } else { o.x = 0; o.y = 0; o.z = 0; o.w = 0; }
    *(int4*)((uint8_t*)wb + frag_addr(r, k)) = o;
  } else if (bid < 6704) {                 // ---- cvt x -> fp8, frag order ----
    int i = ((bid - 5680) * 256 + threadIdx.x) * 16;
    const int r = i >> 9, k = i & 511;
    const float4* p = (const float4*)(x + i);
    int4 o;
    o.x = pk_fp8x4v(p[0], 1.f);
    o.y = pk_fp8x4v(p[1], 1.f);
    o.z = pk_fp8x4v(p[2], 1.f);
    o.w = pk_fp8x4v(p[3], 1.f);
    *(int4*)((uint8_t*)xb + frag_addr(r, k)) = o;
  } else {                                 // ---- zero sg ----
    int i = (bid - 6704) * 256 + threadIdx.x;
    sg[i] = 0.f;
  }
}

// ---- fused GEMM (16*logits = x . (16W)^T, MX-fp8 32x32x64) + row-sum exp ----
// Round-13 = round-12 (fragment-order direct-from-L2, no LDS, no barriers,
// 179 us) + EXPLICIT 2-DEEP FRAGMENT PIPELINE.
// r12's tell: VGPR_Count=76 — the compiler allocated only acc+addressing and
// did NOT prefetch; each kt serialized {issue 16 loads -> waitcnt full L2
// latency -> MFMA}, pinning MfmaUtil at 31%. Here the K-loop is 8 fully-
// unrolled phases (kt x kk) with two NAMED register buffers (compile-time
// indexing only, rule 20): phase p issues buf[(p+1)&1]'s 4 loads BEFORE the
// 4 MFMAs on buf[p&1] — counted vmcnt lets every load ride a full MFMA
// phase (~275 cy) of latency cover.
// Regs: acc 64 + 2x32 frag bufs + addr ~= 150 < 170 cap of (256,3).
// Geometry r12 verbatim: 128x128 tile, 4 waves 2x2, wave tile 64x64;
// fragment loads are 2048-B-contiguous per wave (prep stores frag-order).
// Bounds: cb max = 907 < VPAD/32 = 908; bias=-1e30 for col>=VOCAB.
__global__ void __launch_bounds__(256, 3)
gemm_stats_kernel(const uint8_t* __restrict__ xb, const uint8_t* __restrict__ wb,
                  const float* __restrict__ bias, float* __restrict__ sg) {
  const int tid  = threadIdx.x;
  const int lane = tid & 63;
  const int w    = tid >> 6;       // wave 0..3
  const int l31  = lane & 31;
  const int h    = lane >> 5;      // k-half for 32x32 operands
  const int wr   = (w >> 1) * 64;  // wave row offset in tile
  const int wc   = (w & 1) * 64;   // wave col offset in tile
  const int rowBase = blockIdx.x * 128;  // x rows     (grid.x = 64)
  const int colBase = blockIdx.y * 128;  // vocab cols (grid.y = 227)

  // fragment-order base pointers: 32-row block index * 16384 + lane*32
  const int rbB = blockIdx.x * 4 + (w >> 1) * 2;   // A: rb, rb+1 (ii)
  const int cbB = blockIdx.y * 4 + (w & 1) * 2;    // B: cb, cb+1 (jj)
  const uint8_t* pa = xb + ((size_t)rbB << 14) + lane * 32;
  const uint8_t* pb = wb + ((size_t)cbB << 14) + lane * 32;

  f32x16 acc[2][2];
#pragma unroll
  for (int i = 0; i < 2; ++i)
#pragma unroll
    for (int j = 0; j < 2; ++j)
#pragma unroll
      for (int r = 0; r < 16; ++r) acc[i][j][r] = 0.f;

  // phase p = kt*2+kk (0..7): fragment byte offset p*2048
  auto loadPh = [&](int p, i32x8* aq, i32x8* bq) {
    const size_t off = (size_t)p << 11;
    bq[0] = *(const i32x8*)(pb + off);
    bq[1] = *(const i32x8*)(pb + (1 << 14) + off);
    aq[0] = *(const i32x8*)(pa + off);
    aq[1] = *(const i32x8*)(pa + (1 << 14) + off);
  };
  auto mmaPh = [&](const i32x8* aq, const i32x8* bq) {
#pragma unroll
    for (int ii = 0; ii < 2; ++ii) {
      acc[ii][0] = __builtin_amdgcn_mfma_scale_f32_32x32x64_f8f6f4(
          aq[ii], bq[0], acc[ii][0], 0, 0, 0, 0x7F7F7F7F, 0, 0x7F7F7F7F);
      acc[ii][1] = __builtin_amdgcn_mfma_scale_f32_32x32x64_f8f6f4(
          aq[ii], bq[1], acc[ii][1], 0, 0, 0, 0x7F7F7F7F, 0, 0x7F7F7F7F);
    }
  };

  i32x8 aq0[2], bq0[2], aq1[2], bq1[2];   // two named phase buffers
  loadPh(0, aq0, bq0);
#pragma unroll
  for (int p = 0; p < 8; ++p) {
    if ((p & 1) == 0) {
      if (p < 7) loadPh(p + 1, aq1, bq1);  // prefetch odd phase
      mmaPh(aq0, bq0);
    } else {
      if (p < 7) loadPh(p + 1, aq0, bq0);  // prefetch even phase
      mmaPh(aq1, bq1);
    }
  }

  // ---- epilogue: s_row += sum_j exp(acc/16 + bias)  (r12-verified verbatim) ----
  // 32x32 C/D layout (m74/m101): col = lane&31, row = (reg&3)+8*(reg>>2)+4*h
  float bvl[2];
#pragma unroll
  for (int jj = 0; jj < 2; ++jj) {
    const int col = colBase + wc + jj * 32 + l31;
    bvl[jj] = (col < VOCAB) ? bias[col] * LOG2E : -1e30f;
  }

  float sp[32];  // v = ii*16 + reg
#pragma unroll
  for (int ii = 0; ii < 2; ++ii)
#pragma unroll
    for (int r = 0; r < 16; ++r)
      sp[ii * 16 + r] = exp2f(fmaf(acc[ii][0][r], INV_WSCALE_L2E, bvl[0])) +
                        exp2f(fmaf(acc[ii][1][r], INV_WSCALE_L2E, bvl[1]));

  // stacking reduction over the 32 cols (xor 1..16 stays within the h-half);
  // ends with lane holding the full col-sum for value index v == (lane&31).
  float t1[16];
#pragma unroll
  for (int u = 0; u < 16; ++u) {
    float a = sp[2 * u]     + __shfl_xor(sp[2 * u],     1);
    float b = sp[2 * u + 1] + __shfl_xor(sp[2 * u + 1], 1);
    t1[u] = (l31 & 1) ? b : a;
  }
  float t2[8];
#pragma unroll
  for (int u = 0; u < 8; ++u) {
    float a = t1[2 * u]     + __shfl_xor(t1[2 * u],     2);
    float b = t1[2 * u + 1] + __shfl_xor(t1[2 * u + 1], 2);
    t2[u] = (l31 & 2) ? b : a;
  }
  float t3[4];
#pragma unroll
  for (int u = 0; u < 4; ++u) {
    float a = t2[2 * u]     + __shfl_xor(t2[2 * u],     4);
    float b = t2[2 * u + 1] + __shfl_xor(t2[2 * u + 1], 4);
    t3[u] = (l31 & 4) ? b : a;
  }
  float t4[2];
#pragma unroll
  for (int u = 0; u < 2; ++u) {
    float a = t3[2 * u]     + __shfl_xor(t3[2 * u],     8);
    float b = t3[2 * u + 1] + __shfl_xor(t3[2 * u + 1], 8);
    t4[u] = (l31 & 8) ? b : a;
  }
  {
    float a = t4[0] + __shfl_xor(t4[0], 16);
    float b = t4[1] + __shfl_xor(t4[1], 16);
    float ssum = (l31 & 16) ? b : a;
    const int v = l31;                 // ii = v>>4, reg = v&15
    const int row = rowBase + wr + (v >> 4) * 32 + (v & 3) + 8 * ((v & 15) >> 2) + 4 * h;
    atomicAdd(&sg[row], ssum);
  }
}

// ---- final: loss = log(V+1) - mean(py/s)  (q-term ~7e-10, dropped) ----
__global__ void __launch_bounds__(1024)
finalize_kernel(const float* __restrict__ sg, const float* __restrict__ py,
                float* __restrict__ out) {
  __shared__ float red[1024];
  float a = 0.f;
  for (int i = threadIdx.x; i < NROWS; i += 1024)
    a += py[i] / sg[i];
  red[threadIdx.x] = a;
  __syncthreads();
  for (int st = 512; st > 0; st >>= 1) {
    if (threadIdx.x < st) red[threadIdx.x] += red[threadIdx.x + st];
    __syncthreads();
  }
  if (threadIdx.x == 0)
    out[0] = logf((float)(VOCAB + 1)) - red[0] * (1.f / (float)NROWS);
}

extern "C" void kernel_launch(void* const* d_in, const int* in_sizes, int n_in,
                              void* d_out, int out_size, void* d_ws, size_t ws_size,
                              hipStream_t stream) {
  const float* x = (const float*)d_in[0];
  const int*   y = (const int*)d_in[1];
  const float* W = (const float*)d_in[2];
  const float* b = (const float*)d_in[3];

  char* ws = (char*)d_ws;
  uint8_t* xb = (uint8_t*)ws;                             // 4,194,304 B (frag order)
  uint8_t* wb = (uint8_t*)(ws + 4194304);                 // 14,876,672 B (frag order)
  float*   sg = (float*)(ws + 4194304 + 14876672);        // 32 KiB
  float*   py = sg + NROWS;                               // 32 KiB

  prep_kernel<<<6736, 256, 0, stream>>>(x, W, b, y, (int*)xb, (int*)wb, py, sg);
  gemm_stats_kernel<<<dim3(64, 227), 256, 0, stream>>>(xb, wb, b, sg);
  finalize_kernel<<<1, 1024, 0, stream>>>(sg, py, (float*)d_out);
}